// Round 11
// baseline (588.060 us; speedup 1.0000x reference)
//
#include <hip/hip_runtime.h>

#define ZD 64
#define RD 128
#define HIDDEN 512
#define NSTEP 100
#define OUT_PITCH 6464              // 101*64
#define DT_F 0.01f

static const size_t LW_OFF = 52953088ull;   // 8192*101*64
static const size_t NG_OFF = 52961280ull;   // + 8192

typedef __attribute__((ext_vector_type(4))) float  f32x4;
typedef __attribute__((ext_vector_type(8))) __bf16 bf16x8;
typedef __attribute__((ext_vector_type(4))) short  s16x4;
typedef __attribute__((ext_vector_type(8))) short  s16x8;

__device__ __forceinline__ short f2bs(float f) {
    return __builtin_bit_cast(short, (__bf16)f);
}
__device__ __forceinline__ float bs2f(short s) {
    return __builtin_bit_cast(float, ((unsigned)(unsigned short)s) << 16);
}
__device__ __forceinline__ float tanh_fast(float x) {
    float e = __builtin_amdgcn_exp2f(x * 2.88539008177793f);
    float r = __builtin_amdgcn_rcpf(e + 1.0f);
    return fmaf(-2.0f, r, 1.0f);
}

// ---------------------------------------------------------------------------
// sim_kernel: persistent scan, symmetric wave-group specialization.
// 256 blocks x 1024 threads (16 waves), 32 rows/block split A/B x16.
// Group alpha (waves 0-7) owns half A: phases G2(A) -> U(A) -> G1(A,s+1).
// Group beta (waves 8-15) owns half B: phases G1(B) -> G2(B) -> U(B).
// Every phase co-schedules a DS-heavy task (G2/U) with a VALU-heavy task
// (G1 tanh) on DIFFERENT waves -> pipe mixing by construction.
// Per-wave: G1 = 4 n-tiles (w1f 32 regs, w1t/pre packed bf16), G2 =
// (z-half x K-quarter) (w2f 32 regs), U = 2 elems/thread. ~93 persistent
// regs, peak ~117 < 128 combined -> no spills at 4 waves/SIMD.
// ---------------------------------------------------------------------------
__global__ __launch_bounds__(1024, 1)
void sim_kernel(
    const float* __restrict__ r, const float* __restrict__ noises,
    const float* __restrict__ x0, const float* __restrict__ W1,
    const float* __restrict__ b1, const float* __restrict__ W2,
    const float* __restrict__ b2, const float* __restrict__ bmax,
    const float* __restrict__ bmin, const float* __restrict__ mu,
    float* __restrict__ out)
{
    __shared__ unsigned short Xb[2][16 * 64];         // 4096 B
    __shared__ unsigned short Hs[2][16 * HIDDEN];     // 32768 B
    __shared__ float Ps[2][4][16][76];                // 38912 B
    __shared__ float tT[NSTEP], tG[NSTEP], tSd[NSTEP], tCd[NSTEP], tCs[NSTEP];

    const int tid  = threadIdx.x;
    const int lane = tid & 63;
    const int wave = tid >> 6;       // 0..15
    const int g4   = lane >> 4;      // 0..3
    const int l16  = lane & 15;
    const int row0 = blockIdx.x * 32;
    const int xswz = (l16 & 7) << 3;

    const int grp = wave >> 3;       // 0 = alpha (half A), 1 = beta (half B)
    const int q   = wave & 7;        // role within group
    const int zh  = q & 1, kq = q >> 1;   // G2: z-half, K-quarter

    unsigned short* Xh = Xb[grp];
    unsigned short* Hh = Hs[grp];
    float (*Ph)[16][76] = Ps[grp];

    // ---- step tables ----
    if (tid < NSTEP) {
        float spmax = log1pf(expf(bmax[0]));
        float spmin = log1pf(expf(bmin[0]));
        float a_ = spmax - spmin;
        float c_ = spmin;
        const float PI_ = 3.14159265358979323846f;
        float k = (float)tid;
        float t0 = k * DT_F, t1 = (k + 1.0f) * DT_F;
        float inv2pi = 1.0f / (2.0f * PI_);
        float F0 = a_ * sinf(PI_ * t0) * inv2pi + (0.5f * a_ + c_) * t0;
        float F1 = a_ * sinf(PI_ * t1) * inv2pi + (0.5f * a_ + c_) * t1;
        float al = 1.0f - expf(-2.0f * (F1 - F0));
        float gg = 1.0f - sqrtf(1.0f - al);
        float kap = (gg * gg) / al;
        tT[tid] = t0; tG[tid] = gg; tSd[tid] = sqrtf(al);
        tCd[tid] = -2.0f * kap; tCs[tid] = -2.0f * sqrtf(kap);
    }

    // ---- U indexing: 512 threads of the group cover 16 rows x 64 cols ----
    const int urow = (q << 1) | (lane >> 5);      // 0..15
    const int uc0  = lane & 31;
    const int uc1  = uc0 + 32;
    const size_t grow = (size_t)(row0 + grp * 16 + urow);
    const int uswz = (urow & 7) << 3;

    // ---- x state init + x_t[:,0,:] + Xb ----
    float xu0 = x0[grow * ZD + uc0];
    float xu1 = x0[grow * ZD + uc1];
    out[grow * OUT_PITCH + uc0] = xu0;
    out[grow * OUT_PITCH + uc1] = xu1;
    Xh[(urow * 64 + uc0) ^ uswz] = (unsigned short)f2bs(xu0);
    Xh[(urow * 64 + uc1) ^ uswz] = (unsigned short)f2bs(xu1);
    const float bb0 = b2[uc0], bb1 = b2[uc1];
    float lw = 0.0f;

    // ---- pre-fragments via MFMA (this wave's half): packed bf16 ----
    s16x4 prefb[4];
    {
        bf16x8 rf[4];
        const float* rp = r + (size_t)(row0 + grp * 16 + l16) * RD;
        #pragma unroll
        for (int kc = 0; kc < 4; ++kc) {
            f32x4 lo = *(const f32x4*)(rp + kc * 32 + g4 * 8);
            f32x4 hi = *(const f32x4*)(rp + kc * 32 + g4 * 8 + 4);
            bf16x8 v;
            v[0]=(__bf16)lo[0]; v[1]=(__bf16)lo[1]; v[2]=(__bf16)lo[2]; v[3]=(__bf16)lo[3];
            v[4]=(__bf16)hi[0]; v[5]=(__bf16)hi[1]; v[6]=(__bf16)hi[2]; v[7]=(__bf16)hi[3];
            rf[kc] = v;
        }
        #pragma unroll
        for (int j2 = 0; j2 < 4; ++j2) {
            int n  = (q * 4 + j2) * 16 + l16;
            int n0 = (q * 4 + j2) * 16 + g4 * 4;
            f32x4 acc = *(const f32x4*)(b1 + n0);
            #pragma unroll
            for (int kc = 0; kc < 4; ++kc) {
                bf16x8 w;
                #pragma unroll
                for (int j = 0; j < 8; ++j)
                    w[j] = (__bf16)W1[(size_t)(64 + kc * 32 + g4 * 8 + j) * HIDDEN + n];
                acc = __builtin_amdgcn_mfma_f32_16x16x32_bf16(w, rf[kc], acc, 0, 0, 0);
            }
            s16x4 pb;
            pb[0] = f2bs(acc[0]); pb[1] = f2bs(acc[1]);
            pb[2] = f2bs(acc[2]); pb[3] = f2bs(acc[3]);
            prefb[j2] = pb;
        }
    }

    // ---- persistent weight fragments ----
    bf16x8 w1f[4][2];     // [j2][kc]
    s16x4  w1tb[4];       // t-row of W1, packed bf16
    #pragma unroll
    for (int j2 = 0; j2 < 4; ++j2) {
        int n  = (q * 4 + j2) * 16 + l16;
        int n0 = (q * 4 + j2) * 16 + g4 * 4;
        f32x4 wt = *(const f32x4*)(W1 + (size_t)192 * HIDDEN + n0);
        s16x4 wb;
        wb[0] = f2bs(wt[0]); wb[1] = f2bs(wt[1]);
        wb[2] = f2bs(wt[2]); wb[3] = f2bs(wt[3]);
        w1tb[j2] = wb;
        #pragma unroll
        for (int kc = 0; kc < 2; ++kc) {
            bf16x8 v;
            #pragma unroll
            for (int j = 0; j < 8; ++j)
                v[j] = (__bf16)W1[(size_t)(kc * 32 + g4 * 8 + j) * HIDDEN + n];
            w1f[j2][kc] = v;
        }
    }
    bf16x8 w2f[2][4];     // [z-tile within half][kc within quarter]
    #pragma unroll
    for (int zt2 = 0; zt2 < 2; ++zt2) {
        int n2 = (zh * 2 + zt2) * 16 + l16;
        #pragma unroll
        for (int i = 0; i < 4; ++i) {
            bf16x8 v;
            #pragma unroll
            for (int j = 0; j < 8; ++j)
                v[j] = (__bf16)W2[(size_t)(kq * 128 + i * 32 + g4 * 8 + j) * ZD + n2];
            w2f[zt2][i] = v;
        }
    }

    // ---- phase bodies ----
    auto G1 = [&](float t) {
        s16x8 xb0 = *(const s16x8*)(Xh + ((l16 * 64 + g4 * 8) ^ xswz));
        s16x8 xb1 = *(const s16x8*)(Xh + ((l16 * 64 + 32 + g4 * 8) ^ xswz));
        #pragma unroll
        for (int j2 = 0; j2 < 4; ++j2) {
            int n0 = (q * 4 + j2) * 16 + g4 * 4;
            s16x4 pb = prefb[j2];
            s16x4 wb = w1tb[j2];
            f32x4 acc;
            acc[0] = fmaf(t, bs2f(wb[0]), bs2f(pb[0]));
            acc[1] = fmaf(t, bs2f(wb[1]), bs2f(pb[1]));
            acc[2] = fmaf(t, bs2f(wb[2]), bs2f(pb[2]));
            acc[3] = fmaf(t, bs2f(wb[3]), bs2f(pb[3]));
            acc = __builtin_amdgcn_mfma_f32_16x16x32_bf16(
                w1f[j2][0], __builtin_bit_cast(bf16x8, xb0), acc, 0, 0, 0);
            acc = __builtin_amdgcn_mfma_f32_16x16x32_bf16(
                w1f[j2][1], __builtin_bit_cast(bf16x8, xb1), acc, 0, 0, 0);
            s16x4 hv;
            hv[0] = f2bs(tanh_fast(acc[0]));
            hv[1] = f2bs(tanh_fast(acc[1]));
            hv[2] = f2bs(tanh_fast(acc[2]));
            hv[3] = f2bs(tanh_fast(acc[3]));
            *(s16x4*)(Hh + ((l16 * HIDDEN + n0) ^ xswz)) = hv;
        }
    };
    auto G2 = [&]() {
        int base = l16 * HIDDEN + kq * 128 + g4 * 8;
        s16x8 h0 = *(const s16x8*)(Hh + ((base +  0) ^ xswz));
        s16x8 h1 = *(const s16x8*)(Hh + ((base + 32) ^ xswz));
        s16x8 h2 = *(const s16x8*)(Hh + ((base + 64) ^ xswz));
        s16x8 h3 = *(const s16x8*)(Hh + ((base + 96) ^ xswz));
        f32x4 aA = { 0.f, 0.f, 0.f, 0.f };
        f32x4 aB = { 0.f, 0.f, 0.f, 0.f };
        aA = __builtin_amdgcn_mfma_f32_16x16x32_bf16(
            w2f[0][0], __builtin_bit_cast(bf16x8, h0), aA, 0, 0, 0);
        aB = __builtin_amdgcn_mfma_f32_16x16x32_bf16(
            w2f[1][0], __builtin_bit_cast(bf16x8, h0), aB, 0, 0, 0);
        aA = __builtin_amdgcn_mfma_f32_16x16x32_bf16(
            w2f[0][1], __builtin_bit_cast(bf16x8, h1), aA, 0, 0, 0);
        aB = __builtin_amdgcn_mfma_f32_16x16x32_bf16(
            w2f[1][1], __builtin_bit_cast(bf16x8, h1), aB, 0, 0, 0);
        aA = __builtin_amdgcn_mfma_f32_16x16x32_bf16(
            w2f[0][2], __builtin_bit_cast(bf16x8, h2), aA, 0, 0, 0);
        aB = __builtin_amdgcn_mfma_f32_16x16x32_bf16(
            w2f[1][2], __builtin_bit_cast(bf16x8, h2), aB, 0, 0, 0);
        aA = __builtin_amdgcn_mfma_f32_16x16x32_bf16(
            w2f[0][3], __builtin_bit_cast(bf16x8, h3), aA, 0, 0, 0);
        aB = __builtin_amdgcn_mfma_f32_16x16x32_bf16(
            w2f[1][3], __builtin_bit_cast(bf16x8, h3), aB, 0, 0, 0);
        *(f32x4*)(&Ph[kq][l16][(zh * 2 + 0) * 16 + g4 * 4]) = aA;
        *(f32x4*)(&Ph[kq][l16][(zh * 2 + 1) * 16 + g4 * 4]) = aB;
    };
    auto UP = [&](int s, float nz0, float nz1) {
        float gg = tG[s], sdv = tSd[s], cd = tCd[s], cs = tCs[s];
        float sv0 = ((Ph[0][urow][uc0] + Ph[1][urow][uc0])
                   + (Ph[2][urow][uc0] + Ph[3][urow][uc0])) + bb0;
        float sv1 = ((Ph[0][urow][uc1] + Ph[1][urow][uc1])
                   + (Ph[2][urow][uc1] + Ph[3][urow][uc1])) + bb1;
        float xn0 = xu0 + gg * (2.0f * sv0 - xu0) + sdv * nz0;
        float xn1 = xu1 + gg * (2.0f * sv1 - xu1) + sdv * nz1;
        out[grow * OUT_PITCH + (size_t)(s + 1) * ZD + uc0] = xn0;
        out[grow * OUT_PITCH + (size_t)(s + 1) * ZD + uc1] = xn1;
        Xh[(urow * 64 + uc0) ^ uswz] = (unsigned short)f2bs(xn0);
        Xh[(urow * 64 + uc1) ^ uswz] = (unsigned short)f2bs(xn1);
        lw += cd * (sv0 * sv0 + sv1 * sv1) + cs * (sv0 * nz0 + sv1 * nz1);
        xu0 = xn0; xu1 = xn1;
    };

    __syncthreads();

    if (grp == 0) G1(tT[0]);          // prologue: h(A, 0)
    __syncthreads();

    for (int s = 0; s < NSTEP; ++s) {
        float nz0, nz1;
        if (grp == 0) {               // ph1: G2(A) || G1(B)
            nz0 = noises[(grow * NSTEP + s) * ZD + uc0];
            nz1 = noises[(grow * NSTEP + s) * ZD + uc1];
            G2();
        } else {
            G1(tT[s]);
        }
        __syncthreads();

        if (grp == 0) {               // ph2: U(A) || G2(B)
            UP(s, nz0, nz1);
        } else {
            nz0 = noises[(grow * NSTEP + s) * ZD + uc0];
            nz1 = noises[(grow * NSTEP + s) * ZD + uc1];
            G2();
        }
        __syncthreads();

        if (grp == 0) {               // ph3: G1(A,s+1) || U(B)
            if (s + 1 < NSTEP) G1(tT[s + 1]);
        } else {
            UP(s, nz0, nz1);
        }
        __syncthreads();
    }

    // ---- finalize: log_weights and nabla_g ----
    {
        float m0 = mu[uc0], m1 = mu[uc1];
        float d0 = xu0 - m0, d1 = xu1 - m1;
        out[NG_OFF + grow * ZD + uc0] = d0 - xu0;    // == -mu
        out[NG_OFF + grow * ZD + uc1] = d1 - xu1;
        float part = lw + 0.5f * (xu0 * xu0 + xu1 * xu1)
                   - 0.5f * (d0 * d0 + d1 * d1);
        part += __shfl_xor(part, 1, 64);
        part += __shfl_xor(part, 2, 64);
        part += __shfl_xor(part, 4, 64);
        part += __shfl_xor(part, 8, 64);
        part += __shfl_xor(part, 16, 64);
        if ((lane & 31) == 0) out[LW_OFF + grow] = part;
    }
}

extern "C" void kernel_launch(void* const* d_in, const int* in_sizes, int n_in,
                              void* d_out, int out_size, void* d_ws, size_t ws_size,
                              hipStream_t stream) {
    const float* r      = (const float*)d_in[0];
    const float* noises = (const float*)d_in[1];
    const float* x0     = (const float*)d_in[2];
    const float* W1     = (const float*)d_in[3];
    const float* b1     = (const float*)d_in[4];
    const float* W2     = (const float*)d_in[5];
    const float* b2     = (const float*)d_in[6];
    const float* bmax   = (const float*)d_in[7];
    const float* bmin   = (const float*)d_in[8];
    const float* mu     = (const float*)d_in[9];
    float* out = (float*)d_out;

    sim_kernel<<<256, 1024, 0, stream>>>(r, noises, x0, W1, b1, W2, b2,
                                         bmax, bmin, mu, out);
}

// Round 12
// 237.018 us; speedup vs baseline: 2.4811x; 2.4811x over previous
//
#include <hip/hip_runtime.h>

#define ZD 64
#define RD 128
#define HIDDEN 512
#define NSTEP 100
#define OUT_PITCH 6464              // 101*64
#define DT_F 0.01f
#define ROWS 32
#define HSTR 520                    // Hs row stride (shorts): row*4 banks
#define XSTR 72                     // Xb row stride (shorts)
#define PSTR 76                     // Ps row stride (floats)

static const size_t LW_OFF = 52953088ull;   // 8192*101*64
static const size_t NG_OFF = 52961280ull;   // + 8192

typedef __attribute__((ext_vector_type(2))) float  f32x2;
typedef __attribute__((ext_vector_type(4))) float  f32x4;
typedef __attribute__((ext_vector_type(8))) __bf16 bf16x8;
typedef __attribute__((ext_vector_type(2))) short  s16x2;
typedef __attribute__((ext_vector_type(4))) short  s16x4;
typedef __attribute__((ext_vector_type(8))) short  s16x8;

__device__ __forceinline__ short f2bs(float f) {
    return __builtin_bit_cast(short, (__bf16)f);
}
__device__ __forceinline__ float tanh_fast(float x) {
    float e = __builtin_amdgcn_exp2f(x * 2.88539008177793f);
    float r = __builtin_amdgcn_rcpf(e + 1.0f);
    return fmaf(-2.0f, r, 1.0f);
}

// ---------------------------------------------------------------------------
// sim_kernel: persistent scan. 256 blocks x 1024 threads (16 waves), 32 rows,
// 1 block/CU, 4 waves/SIMD (R8 proven register shape: 64 arch + 64 acc = 128).
// This round: padded LDS strides (Hs 520, Xb 72, Ps 76) replace XOR swizzles.
// Row r lands at bank r*4 -> b128 reads are exactly bank-uniform (8 lanes per
// 16B bank-group), writes <=2-way (free). No register-count change vs R8.
// GEMM1: wave -> 2 n-tiles x 2 m-tiles. GEMM2: wave -> (zh, kq, mtw), each
// Hs read feeds 2 MFMAs; Ps[4] partials summed in update.
// ---------------------------------------------------------------------------
__global__ __launch_bounds__(1024, 1)
void sim_kernel(
    const float* __restrict__ r, const float* __restrict__ noises,
    const float* __restrict__ x0, const float* __restrict__ W1,
    const float* __restrict__ b1, const float* __restrict__ W2,
    const float* __restrict__ b2, const float* __restrict__ bmax,
    const float* __restrict__ bmin, const float* __restrict__ mu,
    float* __restrict__ out)
{
    __shared__ float Ps[4][ROWS][PSTR];               // 38912 B
    __shared__ unsigned short Xb[ROWS * XSTR];        // 4608 B
    __shared__ unsigned short Hs[ROWS * HSTR];        // 33280 B
    __shared__ float w1ts[HIDDEN];                    // 2048 B
    __shared__ float tT[NSTEP], tG[NSTEP], tSd[NSTEP], tCd[NSTEP], tCs[NSTEP];

    const int tid  = threadIdx.x;
    const int lane = tid & 63;
    const int wave = tid >> 6;       // 0..15
    const int g4   = lane >> 4;      // 0..3
    const int l16  = lane & 15;
    const int row0 = blockIdx.x * ROWS;

    // ---- step tables ----
    if (tid < NSTEP) {
        float spmax = log1pf(expf(bmax[0]));
        float spmin = log1pf(expf(bmin[0]));
        float a_ = spmax - spmin;
        float c_ = spmin;
        const float PI_ = 3.14159265358979323846f;
        float k = (float)tid;
        float t0 = k * DT_F, t1 = (k + 1.0f) * DT_F;
        float inv2pi = 1.0f / (2.0f * PI_);
        float F0 = a_ * sinf(PI_ * t0) * inv2pi + (0.5f * a_ + c_) * t0;
        float F1 = a_ * sinf(PI_ * t1) * inv2pi + (0.5f * a_ + c_) * t1;
        float al = 1.0f - expf(-2.0f * (F1 - F0));
        float gg = 1.0f - sqrtf(1.0f - al);
        float kap = (gg * gg) / al;
        tT[tid] = t0; tG[tid] = gg; tSd[tid] = sqrtf(al);
        tCd[tid] = -2.0f * kap; tCs[tid] = -2.0f * sqrtf(kap);
    }
    if (tid < HIDDEN) w1ts[tid] = W1[(size_t)192 * HIDDEN + tid];

    // ---- x state init (update-thread registers) + x_t[:,0,:] + Xb ----
    const int urow = tid >> 5;          // 0..31
    const int c2   = (tid & 31) * 2;    // 0..62
    const size_t ubase = (size_t)(row0 + urow);
    float xr0, xr1;
    {
        f32x2 v = *(const f32x2*)(x0 + ubase * ZD + c2);
        xr0 = v[0]; xr1 = v[1];
        *(f32x2*)(out + ubase * OUT_PITCH + c2) = v;
        s16x2 xv; xv[0] = f2bs(xr0); xv[1] = f2bs(xr1);
        *(s16x2*)(Xb + urow * XSTR + c2) = xv;
    }
    const float bb0 = b2[c2], bb1 = b2[c2 + 1];

    // ---- pre-fragments via MFMA: pref[j2][mt] = b1 + r @ W1r ----
    f32x4 pref[2][2];
    {
        #pragma unroll
        for (int mtt = 0; mtt < 2; ++mtt) {
            bf16x8 rf[4];
            const float* rp = r + (size_t)(row0 + mtt * 16 + l16) * RD;
            #pragma unroll
            for (int kc = 0; kc < 4; ++kc) {
                f32x4 lo = *(const f32x4*)(rp + kc * 32 + g4 * 8);
                f32x4 hi = *(const f32x4*)(rp + kc * 32 + g4 * 8 + 4);
                bf16x8 v;
                v[0]=(__bf16)lo[0]; v[1]=(__bf16)lo[1]; v[2]=(__bf16)lo[2]; v[3]=(__bf16)lo[3];
                v[4]=(__bf16)hi[0]; v[5]=(__bf16)hi[1]; v[6]=(__bf16)hi[2]; v[7]=(__bf16)hi[3];
                rf[kc] = v;
            }
            #pragma unroll
            for (int j2 = 0; j2 < 2; ++j2) {
                int n  = (wave * 2 + j2) * 16 + l16;
                int n0 = (wave * 2 + j2) * 16 + g4 * 4;
                f32x4 acc = *(const f32x4*)(b1 + n0);
                #pragma unroll
                for (int kc = 0; kc < 4; ++kc) {
                    bf16x8 w;
                    #pragma unroll
                    for (int j = 0; j < 8; ++j)
                        w[j] = (__bf16)W1[(size_t)(64 + kc * 32 + g4 * 8 + j) * HIDDEN + n];
                    acc = __builtin_amdgcn_mfma_f32_16x16x32_bf16(w, rf[kc], acc, 0, 0, 0);
                }
                pref[j2][mtt] = acc;
            }
        }
    }

    // ---- persistent weight fragments ----
    bf16x8 w1f[2][2];                // [j2][kc]
    #pragma unroll
    for (int j2 = 0; j2 < 2; ++j2) {
        int n = (wave * 2 + j2) * 16 + l16;
        #pragma unroll
        for (int kc = 0; kc < 2; ++kc) {
            bf16x8 v;
            #pragma unroll
            for (int j = 0; j < 8; ++j)
                v[j] = (__bf16)W1[(size_t)(kc * 32 + g4 * 8 + j) * HIDDEN + n];
            w1f[j2][kc] = v;
        }
    }
    // GEMM2 roles: zh = wave&1 (z-half), kq = (wave>>1)&3 (K-quarter),
    //              mtw = wave>>3 (m-tile). Each h read feeds 2 z-tiles.
    const int zh = wave & 1, kq = (wave >> 1) & 3, mtw = wave >> 3;
    bf16x8 w2f[2][4];
    #pragma unroll
    for (int zt2 = 0; zt2 < 2; ++zt2) {
        int n = (zh * 2 + zt2) * 16 + l16;
        #pragma unroll
        for (int i = 0; i < 4; ++i) {
            bf16x8 v;
            #pragma unroll
            for (int j = 0; j < 8; ++j)
                v[j] = (__bf16)W2[(size_t)(kq * 128 + i * 32 + g4 * 8 + j) * ZD + n];
            w2f[zt2][i] = v;
        }
    }

    float lwacc = 0.0f;

    __syncthreads();

    for (int s = 0; s < NSTEP; ++s) {
        float t = tT[s];
        // noise prefetch for update phase (hidden under 2 barriers)
        f32x2 nz = *(const f32x2*)(noises + (ubase * NSTEP + s) * ZD + c2);

        // ================= GEMM1: h = tanh(x@W1x + pre + t*w1t) ============
        {
            s16x8 xb[2][2];
            #pragma unroll
            for (int mtt = 0; mtt < 2; ++mtt) {
                int m = mtt * 16 + l16;
                xb[mtt][0] = *(const s16x8*)(Xb + m * XSTR + g4 * 8);
                xb[mtt][1] = *(const s16x8*)(Xb + m * XSTR + 32 + g4 * 8);
            }
            #pragma unroll
            for (int j2 = 0; j2 < 2; ++j2) {
                int n0 = (wave * 2 + j2) * 16 + g4 * 4;
                f32x4 wt = *(const f32x4*)(w1ts + n0);
                #pragma unroll
                for (int mtt = 0; mtt < 2; ++mtt) {
                    f32x4 acc = pref[j2][mtt];
                    acc[0] = fmaf(t, wt[0], acc[0]);
                    acc[1] = fmaf(t, wt[1], acc[1]);
                    acc[2] = fmaf(t, wt[2], acc[2]);
                    acc[3] = fmaf(t, wt[3], acc[3]);
                    acc = __builtin_amdgcn_mfma_f32_16x16x32_bf16(
                        w1f[j2][0], __builtin_bit_cast(bf16x8, xb[mtt][0]), acc, 0, 0, 0);
                    acc = __builtin_amdgcn_mfma_f32_16x16x32_bf16(
                        w1f[j2][1], __builtin_bit_cast(bf16x8, xb[mtt][1]), acc, 0, 0, 0);
                    s16x4 hv;
                    hv[0] = f2bs(tanh_fast(acc[0]));
                    hv[1] = f2bs(tanh_fast(acc[1]));
                    hv[2] = f2bs(tanh_fast(acc[2]));
                    hv[3] = f2bs(tanh_fast(acc[3]));
                    int m = mtt * 16 + l16;
                    *(s16x4*)(Hs + m * HSTR + n0) = hv;
                }
            }
        }
        __syncthreads();

        // ====== GEMM2 (z-half x K-quarter x m-tile): partials -> Ps[kq] ====
        {
            int m = mtw * 16 + l16;
            int base = m * HSTR + kq * 128 + g4 * 8;
            f32x4 aA = { 0.f, 0.f, 0.f, 0.f };
            f32x4 aB = { 0.f, 0.f, 0.f, 0.f };
            #pragma unroll
            for (int i = 0; i < 4; ++i) {
                s16x8 h = *(const s16x8*)(Hs + base + i * 32);
                aA = __builtin_amdgcn_mfma_f32_16x16x32_bf16(
                    w2f[0][i], __builtin_bit_cast(bf16x8, h), aA, 0, 0, 0);
                aB = __builtin_amdgcn_mfma_f32_16x16x32_bf16(
                    w2f[1][i], __builtin_bit_cast(bf16x8, h), aB, 0, 0, 0);
            }
            *(f32x4*)(&Ps[kq][m][(zh * 2 + 0) * 16 + g4 * 4]) = aA;
            *(f32x4*)(&Ps[kq][m][(zh * 2 + 1) * 16 + g4 * 4]) = aB;
        }
        __syncthreads();

        // ================= Update (x in registers, lw deferred) ============
        {
            float gg = tG[s], sdv = tSd[s], cd = tCd[s], cs = tCs[s];
            f32x2 p0 = *(const f32x2*)(&Ps[0][urow][c2]);
            f32x2 p1 = *(const f32x2*)(&Ps[1][urow][c2]);
            f32x2 p2 = *(const f32x2*)(&Ps[2][urow][c2]);
            f32x2 p3 = *(const f32x2*)(&Ps[3][urow][c2]);
            float s0 = ((p0[0] + p1[0]) + (p2[0] + p3[0])) + bb0;
            float s1 = ((p0[1] + p1[1]) + (p2[1] + p3[1])) + bb1;
            float xn0 = xr0 + gg * (2.0f * s0 - xr0) + sdv * nz[0];
            float xn1 = xr1 + gg * (2.0f * s1 - xr1) + sdv * nz[1];
            xr0 = xn0; xr1 = xn1;
            f32x2 xv = { xn0, xn1 };
            *(f32x2*)(out + ubase * OUT_PITCH + (size_t)(s + 1) * ZD + c2) = xv;
            s16x2 xb2; xb2[0] = f2bs(xn0); xb2[1] = f2bs(xn1);
            *(s16x2*)(Xb + urow * XSTR + c2) = xb2;
            lwacc += cd * (s0 * s0 + s1 * s1) + cs * (s0 * nz[0] + s1 * nz[1]);
        }
        __syncthreads();
    }

    // ---- finalize: log_weights and nabla_g ----
    {
        float m0 = mu[c2], m1 = mu[c2 + 1];
        float d0 = xr0 - m0, d1 = xr1 - m1;
        f32x2 ng = { d0 - xr0, d1 - xr1 };           // == -mu
        *(f32x2*)(out + NG_OFF + ubase * ZD + c2) = ng;
        float part = lwacc
                   + 0.5f * (xr0 * xr0 + xr1 * xr1) - 0.5f * (d0 * d0 + d1 * d1);
        part += __shfl_xor(part, 1, 64);
        part += __shfl_xor(part, 2, 64);
        part += __shfl_xor(part, 4, 64);
        part += __shfl_xor(part, 8, 64);
        part += __shfl_xor(part, 16, 64);
        if ((tid & 31) == 0) out[LW_OFF + ubase] = part;
    }
}

extern "C" void kernel_launch(void* const* d_in, const int* in_sizes, int n_in,
                              void* d_out, int out_size, void* d_ws, size_t ws_size,
                              hipStream_t stream) {
    const float* r      = (const float*)d_in[0];
    const float* noises = (const float*)d_in[1];
    const float* x0     = (const float*)d_in[2];
    const float* W1     = (const float*)d_in[3];
    const float* b1     = (const float*)d_in[4];
    const float* W2     = (const float*)d_in[5];
    const float* b2     = (const float*)d_in[6];
    const float* bmax   = (const float*)d_in[7];
    const float* bmin   = (const float*)d_in[8];
    const float* mu     = (const float*)d_in[9];
    float* out = (float*)d_out;

    sim_kernel<<<256, 1024, 0, stream>>>(r, noises, x0, W1, b1, W2, b2,
                                         bmax, bmin, mu, out);
}